// Round 10
// baseline (199.620 us; speedup 1.0000x reference)
//
#include <hip/hip_runtime.h>
#include <float.h>

// ReconGraph: out[x][y] = OR over 4 diagonal neighbors of (|d[y+dy][x+dx]-d[y][x]| <= thr),
// OOB neighbor = FLT_MAX (never connects). Output int32 0/1, transposed (out[x*8192+y]).
//
// Round-9: 256x256 tile, every global read/write instruction is a 1 KB contiguous burst.
//  - 8 y-slabs of 32 rows: stage 34 rows x 258 cols in LDS (float4 -> ds_write_b128).
//  - thread t owns x-column t: 3-tap rolling stencil (rows y, y+1, y+2 — FIXED: rounds
//    7/8 rolled a 1-deep history, skipping a row), packs 32 bools/slab into a u32.
//  - store phase: per output x-row, one wave expands the 256-bit mask and writes
//    1 KB contiguous (64 lanes x int4).

constexpr int TX    = 256;
constexpr int TY    = 256;
constexpr int SLAB  = 32;
constexpr int NSLAB = TY / SLAB;   // 8
constexpr int SROWS = SLAB + 2;    // 34
constexpr int SW    = 264;         // row stride floats (16B-aligned); halo at cols 256,258

#define BIG4 make_float4(FLT_MAX, FLT_MAX, FLT_MAX, FLT_MAX)

__global__ __launch_bounds__(256, 3)
void recon_kernel(const float* __restrict__ d, const float* __restrict__ thrp,
                  int* __restrict__ out) {
    __shared__ float    sl[SROWS][SW];   // 35.9 KB
    __shared__ unsigned msk[TX][9];      // 9.2 KB, stride 9 words -> conflict-free

    const float thr = thrp[0];
    const int bx = blockIdx.x, by = blockIdx.y;
    const int tid  = threadIdx.x;
    const int lane = tid & 63;
    const int wave = tid >> 6;
    const int gx0 = bx * TX;
    const int gy0 = by * TY;

    const int t    = tid;                     // owned x-column (0..255)
    const int lcol = (t == 0) ? 258 : t - 1;  // x-1 (left halo at col 258)
    const int rcol = t + 1;                   // x+1 (t=255 -> right halo col 256)

    for (int s = 0; s < NSLAB; ++s) {
        const int ys0 = gy0 + s * SLAB;       // need rows ys0-1 .. ys0+32

        // ---- stage interior: wave handles row r; 64 lanes = one 1 KB contiguous load
#pragma unroll
        for (int i = 0; i < 9; ++i) {
            const int r = i * 4 + wave;       // wave-uniform
            if (r < SROWS) {
                const int yy = ys0 - 1 + r;
                float4 v = BIG4;
                if ((unsigned)yy < 8192u)
                    v = *reinterpret_cast<const float4*>(d + ((size_t)yy << 13) + gx0 + 4 * lane);
                *reinterpret_cast<float4*>(&sl[r][4 * lane]) = v;
            }
        }
        // ---- stage halo columns: 68 tasks (row, side)
        if (tid < 2 * SROWS) {
            const int r    = tid >> 1;
            const int side = tid & 1;         // 0: x=gx0+256 -> col 256 ; 1: x=gx0-1 -> col 258
            const int yy = ys0 - 1 + r;
            const int xx = side ? gx0 - 1 : gx0 + TX;
            float v = FLT_MAX;
            if ((unsigned)yy < 8192u && (unsigned)xx < 8192u)
                v = d[((size_t)yy << 13) + xx];
            sl[r][side ? 258 : 256] = v;
        }
        __syncthreads();

        // ---- 3-tap rolling stencil down owned column, pack 32 results into a u32
        // At iter y: top diag = slab row y (clA/crA), bottom diag = slab row y+2 (clC/crC).
        unsigned m = 0;
        float clA = sl[0][lcol], crA = sl[0][rcol];   // row y
        float clB = sl[1][lcol], crB = sl[1][rcol];   // row y+1
#pragma unroll
        for (int y = 0; y < SLAB; ++y) {
            const float ctr = sl[y + 1][t];
            const float clC = sl[y + 2][lcol];        // row y+2
            const float crC = sl[y + 2][rcol];
            const bool conn = (fabsf(clA - ctr) <= thr) |
                              (fabsf(crA - ctr) <= thr) |
                              (fabsf(clC - ctr) <= thr) |
                              (fabsf(crC - ctr) <= thr);
            m |= (conn ? 1u : 0u) << y;
            clA = clB; clB = clC;
            crA = crB; crB = crC;
        }
        msk[t][s] = m;
        __syncthreads();                      // orders msk writes; protects sl for next slab
    }

    // ---- store: wave expands one x-row's 256-bit mask -> 1 KB contiguous write
    const unsigned nsh = (lane & 7) * 4;
    for (int j = 0; j < 64; ++j) {
        const int xr = j * 4 + wave;
        const unsigned w = msk[xr][lane >> 3];   // 8 words/wave, broadcast in 8-lane groups
        int4 o;
        o.x = (int)((w >> (nsh + 0)) & 1u);
        o.y = (int)((w >> (nsh + 1)) & 1u);
        o.z = (int)((w >> (nsh + 2)) & 1u);
        o.w = (int)((w >> (nsh + 3)) & 1u);
        *reinterpret_cast<int4*>(out + ((size_t)(gx0 + xr) << 13) + gy0 + 4 * lane) = o;
    }
}

extern "C" void kernel_launch(void* const* d_in, const int* in_sizes, int n_in,
                              void* d_out, int out_size, void* d_ws, size_t ws_size,
                              hipStream_t stream) {
    const float* d   = (const float*)d_in[0];
    const float* thr = (const float*)d_in[1];
    int* out = (int*)d_out;
    dim3 grid(8192 / TX, 8192 / TY);   // 32 x 32
    recon_kernel<<<grid, dim3(256), 0, stream>>>(d, thr, out);
}

// Round 12
// 132.425 us; speedup vs baseline: 1.5074x; 1.5074x over previous
//
#include <hip/hip_runtime.h>
#include <float.h>

// ReconGraph: out[x][y] = OR over 4 diagonal neighbors of (|d[y+dy][x+dx]-d[y][x]| <= thr),
// OOB neighbor = FLT_MAX (never connects). Output int32 0/1, transposed (out[x*8192+y]).
//
// Round-11: transpose in the COMPRESSED (bit) domain so both heavy HBM streams are
// fully sequential:
//   pass 1: row-order streaming stencil -> bit-packed mask (8 MB) in d_ws.
//           8 px/lane, rolling 3-row registers, no LDS, no barriers.
//   pass 2: read mask words, expand bits -> int32, write output in output-row order
//           (1 KB contiguous per store instruction).
// Fallback (ws too small): round-6 register-stencil kernel (known-good, 154 us).

// ---------------- pass 1 ----------------
__device__ __forceinline__ void load_row(const float* __restrict__ d, int y, int x0, int xl,
                                         float* r, float& eL, float& eR) {
    if ((unsigned)y < 8192u) {
        const float4 a = *reinterpret_cast<const float4*>(d + ((size_t)y << 13) + xl);
        const float4 b = *reinterpret_cast<const float4*>(d + ((size_t)y << 13) + xl + 4);
        r[0] = a.x; r[1] = a.y; r[2] = a.z; r[3] = a.w;
        r[4] = b.x; r[5] = b.y; r[6] = b.z; r[7] = b.w;
        eL = (x0 > 0)          ? d[((size_t)y << 13) + x0 - 1]   : FLT_MAX;
        eR = (x0 + 512 < 8192) ? d[((size_t)y << 13) + x0 + 512] : FLT_MAX;
    } else {
#pragma unroll
        for (int i = 0; i < 8; ++i) r[i] = FLT_MAX;
        eL = eR = FLT_MAX;
    }
}

__global__ __launch_bounds__(256, 4)
void pass1_kernel(const float* __restrict__ d, const float* __restrict__ thrp,
                  unsigned char* __restrict__ bm) {
    const float thr = thrp[0];
    const int tid  = threadIdx.x;
    const int lane = tid & 63;
    const int wid  = blockIdx.x * 4 + (tid >> 6);   // 0..4095
    const int strip = wid & 15;                     // 16 strips of 512 px
    const int band  = wid >> 4;                     // 256 bands of 32 rows
    const int x0 = strip * 512;
    const int yb = band * 32;
    const int xl = x0 + 8 * lane;                   // lane's 8-px base

    float rA[8], rB[8], rC[8], rD[8];               // rows y-1, y, y+1, prefetch y+2
    float eA, eB, eC, eD, fA, fB, fC, fD;           // strip-edge scalars (left/right)

    load_row(d, yb - 1, x0, xl, rA, eA, fA);
    load_row(d, yb,     x0, xl, rB, eB, fB);
    load_row(d, yb + 1, x0, xl, rC, eC, fC);

    for (int y = yb; y < yb + 32; ++y) {
        const int yn = y + 2;                       // prefetch (wave-uniform guard)
        if (yn <= yb + 32) load_row(d, yn, x0, xl, rD, eD, fD);

        // cross-lane x-halo for diagonal rows
        float lA = __shfl_up(rA[7], 1);   if (lane == 0)  lA = eA;
        float hA = __shfl_down(rA[0], 1); if (lane == 63) hA = fA;
        float lC = __shfl_up(rC[7], 1);   if (lane == 0)  lC = eC;
        float hC = __shfl_down(rC[0], 1); if (lane == 63) hC = fC;

        unsigned byte = 0;
#pragma unroll
        for (int k = 0; k < 8; ++k) {
            const float c  = rB[k];
            const float tl = (k == 0) ? lA : rA[k - 1];
            const float tr = (k == 7) ? hA : rA[k + 1];
            const float bl = (k == 0) ? lC : rC[k - 1];
            const float br = (k == 7) ? hC : rC[k + 1];
            const bool conn = (fabsf(tl - c) <= thr) | (fabsf(tr - c) <= thr) |
                              (fabsf(bl - c) <= thr) | (fabsf(br - c) <= thr);
            byte |= (conn ? 1u : 0u) << k;
        }
        bm[(size_t)y * 1024 + (x0 >> 3) + lane] = (unsigned char)byte;

#pragma unroll
        for (int i = 0; i < 8; ++i) { rA[i] = rB[i]; rB[i] = rC[i]; rC[i] = rD[i]; }
        eA = eB; eB = eC; eC = eD;
        fA = fB; fB = fC; fC = fD;
    }
}

// ---------------- pass 2 ----------------
__global__ __launch_bounds__(256, 8)
void pass2_kernel(const unsigned char* __restrict__ bm, int* __restrict__ out) {
    const int tid  = threadIdx.x;
    const int lane = tid & 63;
    const int wave = tid >> 6;
    const int xt = blockIdx.x >> 3;                 // 128 x-tiles of 64 output rows
    const int yw = blockIdx.x & 7;
    const int x0 = xt * 64;
    const int y0 = (yw * 4 + wave) * 256;           // wave's 256-y window

    // lane loads 4 mask words: rows y0+4*lane .. +3, byte-cols [8*xt, 8*xt+8)
    uint2 w[4];
#pragma unroll
    for (int j = 0; j < 4; ++j)
        w[j] = *reinterpret_cast<const uint2*>(bm + (size_t)(y0 + 4 * lane + j) * 1024 + xt * 8);

#pragma unroll
    for (int r = 0; r < 64; ++r) {                  // output row x0+r; bit r of each word
        int4 o;
        if (r < 32) {
            o.x = (int)((w[0].x >> r) & 1u);
            o.y = (int)((w[1].x >> r) & 1u);
            o.z = (int)((w[2].x >> r) & 1u);
            o.w = (int)((w[3].x >> r) & 1u);
        } else {
            o.x = (int)((w[0].y >> (r - 32)) & 1u);
            o.y = (int)((w[1].y >> (r - 32)) & 1u);
            o.z = (int)((w[2].y >> (r - 32)) & 1u);
            o.w = (int)((w[3].y >> (r - 32)) & 1u);
        }
        *reinterpret_cast<int4*>(out + ((size_t)(x0 + r) << 13) + y0 + 4 * lane) = o;
    }
}

// ---------------- fallback (round-6, known-good) ----------------
#define BIG4 make_float4(FLT_MAX, FLT_MAX, FLT_MAX, FLT_MAX)

template<bool EDGE>
__device__ __forceinline__ void recon_body(const float* __restrict__ d, float thr,
                                           int* __restrict__ out, int bx, int by, int tid) {
    const int xq = tid & 15;
    const int yq = tid >> 4;
    const int gx = bx * 64 + 4 * xq;
    const int gy = by * 64 + 4 * yq;
    float s[6][6];
#pragma unroll
    for (int j = 0; j < 6; ++j) {
        const int yy = gy - 1 + j;
        float4 a, b, c;
        if (!EDGE) {
            const float4* p = (const float4*)(d + ((size_t)yy << 13) + gx);
            a = p[-1]; b = p[0]; c = p[1];
        } else {
            const bool yok = (unsigned)yy < 8192u;
            const float4* p = (const float4*)(d + ((size_t)(yok ? yy : 0) << 13) + gx);
            a = (yok && gx >= 4)       ? p[-1] : BIG4;
            b = yok                    ? p[0]  : BIG4;
            c = (yok && gx + 7 < 8192) ? p[1]  : BIG4;
        }
        s[j][0] = a.w; s[j][1] = b.x; s[j][2] = b.y;
        s[j][3] = b.z; s[j][4] = b.w; s[j][5] = c.x;
    }
#pragma unroll
    for (int i = 0; i < 4; ++i) {
        int r[4];
#pragma unroll
        for (int k = 0; k < 4; ++k) {
            const float ctr = s[k + 1][i + 1];
            const bool conn = (fabsf(s[k][i]     - ctr) <= thr) |
                              (fabsf(s[k][i + 2] - ctr) <= thr) |
                              (fabsf(s[k + 2][i]     - ctr) <= thr) |
                              (fabsf(s[k + 2][i + 2] - ctr) <= thr);
            r[k] = conn ? 1 : 0;
        }
        *reinterpret_cast<int4*>(out + ((size_t)(gx + i) << 13) + gy) =
            make_int4(r[0], r[1], r[2], r[3]);
    }
}

__global__ __launch_bounds__(256, 4)
void recon_fallback(const float* __restrict__ d, const float* __restrict__ thrp,
                    int* __restrict__ out) {
    const float thr = thrp[0];
    const int bx = blockIdx.x, by = blockIdx.y;
    if (bx >= 1 && bx <= 126 && by >= 1 && by <= 126)
        recon_body<false>(d, thr, out, bx, by, threadIdx.x);
    else
        recon_body<true>(d, thr, out, bx, by, threadIdx.x);
}

extern "C" void kernel_launch(void* const* d_in, const int* in_sizes, int n_in,
                              void* d_out, int out_size, void* d_ws, size_t ws_size,
                              hipStream_t stream) {
    const float* d   = (const float*)d_in[0];
    const float* thr = (const float*)d_in[1];
    int* out = (int*)d_out;
    const size_t BM_BYTES = (size_t)8192 * 1024;   // 8 MB bit-packed mask

    if (ws_size >= BM_BYTES) {
        unsigned char* bm = (unsigned char*)d_ws;
        pass1_kernel<<<1024, 256, 0, stream>>>(d, thr, bm);
        pass2_kernel<<<1024, 256, 0, stream>>>(bm, out);
    } else {
        recon_fallback<<<dim3(128, 128), 256, 0, stream>>>(d, thr, out);
    }
}